// Round 2
// baseline (5273.671 us; speedup 1.0000x reference)
//
#include <hip/hip_runtime.h>

#define TPB 256

constexpr int NG = 64, NN = 1000;
constexpr int Nn = NG * NN;          // 64000 nodes
constexpr int Ne = Nn * 32;          // 2048000 edges
constexpr int HID = 3840;
constexpr float EPS = 1e-5f;

// ---------------- workspace layout (float offsets) ----------------
constexpr size_t OFF_DEG = 0;                        // Nn floats (deg -> dinv in place)
constexpr size_t OFF_A1  = 64000;                    // HID
constexpr size_t OFF_B1  = OFF_A1 + HID;             // HID
constexpr size_t OFF_A2  = OFF_B1 + HID;             // 128
constexpr size_t OFF_B2  = OFF_A2 + 128;             // 128  (ends 71936 < 72000)
constexpr size_t OFF_H   = 72000;                    // Nn*100 (h buffer, reused in-place all layers)
constexpr size_t OFF_T   = OFF_H + (size_t)Nn * 100; // Nn*64
constexpr size_t OFF_Y   = OFF_T + (size_t)Nn * 64;  // Nn*64 (scatter accumulator)
constexpr size_t WS_FLOATS = OFF_Y + (size_t)Nn * 64; // 14,664,000 floats = 58.7 MB

// ---------------- small prep kernels ----------------
__global__ __launch_bounds__(TPB) void prep_bn(
    const float* __restrict__ b1, const float* __restrict__ g1,
    const float* __restrict__ be1, const float* __restrict__ m1,
    const float* __restrict__ v1,
    const float* __restrict__ b2, const float* __restrict__ g2,
    const float* __restrict__ be2, const float* __restrict__ m2,
    const float* __restrict__ v2,
    float* __restrict__ A1, float* __restrict__ B1,
    float* __restrict__ A2, float* __restrict__ B2)
{
    int i = blockIdx.x * TPB + threadIdx.x;
    if (i < HID) {
        float s = g1[i] * rsqrtf(v1[i] + EPS);
        A1[i] = s;
        B1[i] = fmaf(b1[i] - m1[i], s, be1[i]);
    }
    int k = i - HID;
    if (k >= 0 && k < 100) {
        float s = g2[k] * rsqrtf(v2[k] + EPS);
        A2[k] = s;
        B2[k] = fmaf(b2[k] - m2[k], s, be2[k]);
    }
}

__global__ __launch_bounds__(TPB) void deg_init(float* __restrict__ deg)
{
    int i = blockIdx.x * TPB + threadIdx.x;
    if (i < Nn) deg[i] = 1.f;
}

__global__ __launch_bounds__(TPB) void deg_count(const int* __restrict__ dst,
                                                 float* __restrict__ deg)
{
    int e = blockIdx.x * TPB + threadIdx.x;
    if (e < Ne) atomicAdd(&deg[dst[e]], 1.f);
}

__global__ __launch_bounds__(TPB) void deg_fin(float* __restrict__ deg)
{
    int i = blockIdx.x * TPB + threadIdx.x;
    if (i < Nn) deg[i] = rsqrtf(deg[i]);
}

// ---------------- fused FFN: h0 = BN2(ReLU(BN1(x@W1+b1)) @ W2 + b2) ----------------
// 32 nodes / block, 256 threads, stream 60 chunks of 64 hidden units.
__global__ __launch_bounds__(TPB, 2) void ffn_kernel(
    const float* __restrict__ x, const float* __restrict__ W1,
    const float* __restrict__ W2,
    const float* __restrict__ cA1, const float* __restrict__ cB1,
    const float* __restrict__ cA2, const float* __restrict__ cB2,
    float* __restrict__ h0)
{
    __shared__ __align__(16) float xs[32][104];   // x tile
    __shared__ __align__(16) float w1s[100][64];  // W1 chunk
    __shared__ __align__(16) float ts[32][68];    // relu(bn1(.)) chunk
    __shared__ __align__(16) float w2s[64][128];  // W2 chunk (cols padded/zeroed)
    __shared__ float a1s[64], b1s[64];

    const int tid = threadIdx.x;
    const int nbase = blockIdx.x * 32;

    // stage x tile (coalesced)
    for (int idx = tid; idx < 32 * 100; idx += TPB) {
        int n = idx / 100, i = idx - n * 100;
        xs[n][i] = x[(size_t)(nbase + n) * 100 + i];
    }

    // phase-1 mapping: 4 consecutive j's x 2 nodes per thread
    const int kk  = tid & 15;      // j-group
    const int np  = tid >> 4;      // node pair 0..15
    const int jj0 = kk * 4;
    const int na  = np * 2, nb = na + 1;
    // phase-2 mapping: 16 consecutive k's x 1 node per thread
    const int n2 = tid >> 3;       // 0..31
    const int kg = tid & 7;        // k base = kg*16

    float acc[16];
#pragma unroll
    for (int u = 0; u < 16; ++u) acc[u] = 0.f;

    for (int c = 0; c < HID / 64; ++c) {
        const int j0 = c * 64;
        __syncthreads();   // protect previous chunk's LDS reads
        for (int idx = tid; idx < 100 * 64; idx += TPB) {
            int i = idx >> 6, jj = idx & 63;
            w1s[i][jj] = W1[(size_t)i * HID + j0 + jj];
        }
        for (int idx = tid; idx < 64 * 128; idx += TPB) {
            int r = idx >> 7, k = idx & 127;
            w2s[r][k] = (k < 100) ? W2[(size_t)(j0 + r) * 100 + k] : 0.f;
        }
        if (tid < 64) { a1s[tid] = cA1[j0 + tid]; b1s[tid] = cB1[j0 + tid]; }
        __syncthreads();

        // phase 1: t[n][j] = relu(dot(x[n],W1[:,j])*A1[j] + B1[j])
        float tv[8];
#pragma unroll
        for (int u = 0; u < 8; ++u) tv[u] = 0.f;
#pragma unroll 2
        for (int i = 0; i < 100; ++i) {
            float4 wv = *(const float4*)&w1s[i][jj0];
            float xa = xs[na][i], xb = xs[nb][i];
            tv[0] = fmaf(xa, wv.x, tv[0]); tv[1] = fmaf(xa, wv.y, tv[1]);
            tv[2] = fmaf(xa, wv.z, tv[2]); tv[3] = fmaf(xa, wv.w, tv[3]);
            tv[4] = fmaf(xb, wv.x, tv[4]); tv[5] = fmaf(xb, wv.y, tv[5]);
            tv[6] = fmaf(xb, wv.z, tv[6]); tv[7] = fmaf(xb, wv.w, tv[7]);
        }
#pragma unroll
        for (int u = 0; u < 4; ++u) {
            int jj = jj0 + u;
            ts[na][jj] = fmaxf(fmaf(tv[u],     a1s[jj], b1s[jj]), 0.f);
            ts[nb][jj] = fmaxf(fmaf(tv[4 + u], a1s[jj], b1s[jj]), 0.f);
        }
        __syncthreads();

        // phase 2: acc[k] += t[n2][jj] * W2[jj][k]
#pragma unroll 4
        for (int jj = 0; jj < 64; ++jj) {
            float tvv = ts[n2][jj];
            const float4* wp = (const float4*)&w2s[jj][kg * 16];
            float4 w0 = wp[0], w1v = wp[1], w2v = wp[2], w3v = wp[3];
            acc[0]  = fmaf(tvv, w0.x,  acc[0]);  acc[1]  = fmaf(tvv, w0.y,  acc[1]);
            acc[2]  = fmaf(tvv, w0.z,  acc[2]);  acc[3]  = fmaf(tvv, w0.w,  acc[3]);
            acc[4]  = fmaf(tvv, w1v.x, acc[4]);  acc[5]  = fmaf(tvv, w1v.y, acc[5]);
            acc[6]  = fmaf(tvv, w1v.z, acc[6]);  acc[7]  = fmaf(tvv, w1v.w, acc[7]);
            acc[8]  = fmaf(tvv, w2v.x, acc[8]);  acc[9]  = fmaf(tvv, w2v.y, acc[9]);
            acc[10] = fmaf(tvv, w2v.z, acc[10]); acc[11] = fmaf(tvv, w2v.w, acc[11]);
            acc[12] = fmaf(tvv, w3v.x, acc[12]); acc[13] = fmaf(tvv, w3v.y, acc[13]);
            acc[14] = fmaf(tvv, w3v.z, acc[14]); acc[15] = fmaf(tvv, w3v.w, acc[15]);
        }
    }

    // epilogue: BN2 (no relu)
#pragma unroll
    for (int u = 0; u < 16; ++u) {
        int k = kg * 16 + u;
        if (k < 100)
            h0[(size_t)(nbase + n2) * 100 + k] = fmaf(acc[u], cA2[k], cB2[k]);
    }
}

// ---------------- GCN layer kernels ----------------
// t[n,f] = dinv[n] * dot(h[n,:], Wc[:,f])
template <int FI2, int FO2>
__global__ __launch_bounds__(TPB) void gcn_transform(
    const float* __restrict__ h, const float* __restrict__ Wc,
    const float* __restrict__ dinv, float* __restrict__ t)
{
    __shared__ float wcs[FI2 * FO2];
    for (int idx = threadIdx.x; idx < FI2 * FO2; idx += TPB) wcs[idx] = Wc[idx];
    __syncthreads();
    int gid = blockIdx.x * TPB + threadIdx.x;
    int n = gid / FO2;
    int f = gid - n * FO2;
    const float* hr = h + (size_t)n * FI2;
    float a = 0.f;
#pragma unroll
    for (int i = 0; i < FI2; ++i) a = fmaf(hr[i], wcs[i * FO2 + f], a);
    t[gid] = a * dinv[n];
}

template <int FO2, int LOG2>
__global__ __launch_bounds__(TPB) void gcn_scatter(
    const int* __restrict__ src, const int* __restrict__ dst,
    const float* __restrict__ t, float* __restrict__ acc)
{
    int gid = blockIdx.x * TPB + threadIdx.x;
    int e = gid >> LOG2;
    int f = gid & (FO2 - 1);
    int s = src[e], d = dst[e];
    atomicAdd(&acc[(size_t)d * FO2 + f], t[(size_t)s * FO2 + f]);
}

// h_out = relu(dinv[n]*(acc + t) + bc[f])  -- written in-place over dead h
template <int FO2, int LOG2>
__global__ __launch_bounds__(TPB) void gcn_finalize(
    const float* __restrict__ acc, const float* __restrict__ t,
    const float* __restrict__ dinv, const float* __restrict__ bc,
    float* __restrict__ hout)
{
    int gid = blockIdx.x * TPB + threadIdx.x;
    int n = gid >> LOG2;
    int f = gid & (FO2 - 1);
    hout[gid] = fmaxf(fmaf(dinv[n], acc[gid] + t[gid], bc[f]), 0.f);
}

// out[g,c] = sum_i h5flat[g*4000+i] * Wf[i,c] + bf[c]
__global__ __launch_bounds__(TPB) void final_fc(
    const float* __restrict__ h5, const float* __restrict__ Wf,
    const float* __restrict__ bfv, float* __restrict__ out)
{
    int g = blockIdx.x;
    float a0 = 0.f, a1 = 0.f;
    for (int i = threadIdx.x; i < NN * 4; i += TPB) {
        float hv = h5[(size_t)g * (NN * 4) + i];
        a0 = fmaf(hv, Wf[2 * i],     a0);
        a1 = fmaf(hv, Wf[2 * i + 1], a1);
    }
#pragma unroll
    for (int off = 32; off > 0; off >>= 1) {
        a0 += __shfl_down(a0, off);
        a1 += __shfl_down(a1, off);
    }
    __shared__ float r0[4], r1[4];
    int wid = threadIdx.x >> 6, lane = threadIdx.x & 63;
    if (lane == 0) { r0[wid] = a0; r1[wid] = a1; }
    __syncthreads();
    if (threadIdx.x == 0) {
        out[g * 2 + 0] = r0[0] + r0[1] + r0[2] + r0[3] + bfv[0];
        out[g * 2 + 1] = r1[0] + r1[1] + r1[2] + r1[3] + bfv[1];
    }
}

// ---------------- launch ----------------
extern "C" void kernel_launch(void* const* d_in, const int* in_sizes, int n_in,
                              void* d_out, int out_size, void* d_ws, size_t ws_size,
                              hipStream_t stream)
{
    const float* x   = (const float*)d_in[0];
    const int*   ei  = (const int*)d_in[1];
    const float* W1  = (const float*)d_in[2];
    const float* b1  = (const float*)d_in[3];
    const float* g1  = (const float*)d_in[4];
    const float* be1 = (const float*)d_in[5];
    const float* m1  = (const float*)d_in[6];
    const float* v1  = (const float*)d_in[7];
    const float* W2  = (const float*)d_in[8];
    const float* b2  = (const float*)d_in[9];
    const float* g2  = (const float*)d_in[10];
    const float* be2 = (const float*)d_in[11];
    const float* m2  = (const float*)d_in[12];
    const float* v2  = (const float*)d_in[13];
    const float* Wf  = (const float*)d_in[14];
    const float* bfv = (const float*)d_in[15];
    const float* Wc[5]  = {(const float*)d_in[16], (const float*)d_in[18],
                           (const float*)d_in[20], (const float*)d_in[22],
                           (const float*)d_in[24]};
    const float* bc[5]  = {(const float*)d_in[17], (const float*)d_in[19],
                           (const float*)d_in[21], (const float*)d_in[23],
                           (const float*)d_in[25]};

    const int* srcp = ei;
    const int* dstp = ei + Ne;

    float* ws  = (float*)d_ws;
    float* deg = ws + OFF_DEG;   // becomes dinv
    float* A1  = ws + OFF_A1;
    float* B1  = ws + OFF_B1;
    float* A2  = ws + OFF_A2;
    float* B2  = ws + OFF_B2;
    float* H   = ws + OFF_H;     // node features, reused in-place across layers
    float* T   = ws + OFF_T;
    float* Y   = ws + OFF_Y;
    float* out = (float*)d_out;

    // degree / dinv
    deg_init<<<Nn / TPB, TPB, 0, stream>>>(deg);
    deg_count<<<Ne / TPB, TPB, 0, stream>>>(dstp, deg);
    deg_fin<<<Nn / TPB, TPB, 0, stream>>>(deg);

    // BN constants
    prep_bn<<<(HID + 100 + TPB - 1) / TPB, TPB, 0, stream>>>(
        b1, g1, be1, m1, v1, b2, g2, be2, m2, v2, A1, B1, A2, B2);

    // fused FFN -> H = h0 [Nn,100]
    ffn_kernel<<<Nn / 32, TPB, 0, stream>>>(x, W1, W2, A1, B1, A2, B2, H);

    // ---- GCN layer 1: H(100) -> H(64) ----
    gcn_transform<100, 64><<<(size_t)Nn * 64 / TPB, TPB, 0, stream>>>(H, Wc[0], deg, T);
    hipMemsetAsync(Y, 0, (size_t)Nn * 64 * sizeof(float), stream);
    gcn_scatter<64, 6><<<(size_t)Ne * 64 / TPB, TPB, 0, stream>>>(srcp, dstp, T, Y);
    gcn_finalize<64, 6><<<(size_t)Nn * 64 / TPB, TPB, 0, stream>>>(Y, T, deg, bc[0], H);

    // ---- layer 2: H(64) -> H(32) ----
    gcn_transform<64, 32><<<(size_t)Nn * 32 / TPB, TPB, 0, stream>>>(H, Wc[1], deg, T);
    hipMemsetAsync(Y, 0, (size_t)Nn * 32 * sizeof(float), stream);
    gcn_scatter<32, 5><<<(size_t)Ne * 32 / TPB, TPB, 0, stream>>>(srcp, dstp, T, Y);
    gcn_finalize<32, 5><<<(size_t)Nn * 32 / TPB, TPB, 0, stream>>>(Y, T, deg, bc[1], H);

    // ---- layer 3: H(32) -> H(16) ----
    gcn_transform<32, 16><<<(size_t)Nn * 16 / TPB, TPB, 0, stream>>>(H, Wc[2], deg, T);
    hipMemsetAsync(Y, 0, (size_t)Nn * 16 * sizeof(float), stream);
    gcn_scatter<16, 4><<<(size_t)Ne * 16 / TPB, TPB, 0, stream>>>(srcp, dstp, T, Y);
    gcn_finalize<16, 4><<<(size_t)Nn * 16 / TPB, TPB, 0, stream>>>(Y, T, deg, bc[2], H);

    // ---- layer 4: H(16) -> H(8) ----
    gcn_transform<16, 8><<<(size_t)Nn * 8 / TPB, TPB, 0, stream>>>(H, Wc[3], deg, T);
    hipMemsetAsync(Y, 0, (size_t)Nn * 8 * sizeof(float), stream);
    gcn_scatter<8, 3><<<(size_t)Ne * 8 / TPB, TPB, 0, stream>>>(srcp, dstp, T, Y);
    gcn_finalize<8, 3><<<(size_t)Nn * 8 / TPB, TPB, 0, stream>>>(Y, T, deg, bc[3], H);

    // ---- layer 5: H(8) -> H(4) ----
    gcn_transform<8, 4><<<(size_t)Nn * 4 / TPB, TPB, 0, stream>>>(H, Wc[4], deg, T);
    hipMemsetAsync(Y, 0, (size_t)Nn * 4 * sizeof(float), stream);
    gcn_scatter<4, 2><<<(size_t)Ne * 4 / TPB, TPB, 0, stream>>>(srcp, dstp, T, Y);
    gcn_finalize<4, 2><<<(size_t)Nn * 4 / TPB, TPB, 0, stream>>>(Y, T, deg, bc[4], H);

    // final FC (H now holds [Nn,4] == [64, 4000] flat)
    final_fc<<<NG, TPB, 0, stream>>>(H, Wf, bfv, out);
}

// Round 3
// 1802.764 us; speedup vs baseline: 2.9253x; 2.9253x over previous
//
#include <hip/hip_runtime.h>

#define TPB 256

constexpr int NG = 64, NN = 1000;
constexpr int Nn = NG * NN;          // 64000 nodes
constexpr int Ne = Nn * 32;          // 2048000 edges
constexpr int HID = 3840;
constexpr float EPS = 1e-5f;

// ---------------- workspace layout (BYTE offsets) ----------------
// deg[Nn] | A1[3840] B1[3840] A2[128] B2[128] | H[Nn*100 f32] | T[Nn*64 f32] | Y[Nn*64 f32]
// W1F/W2F (bf16 frag-major weights) ALIAS the Y region: they are consumed by ffn_mfma
// before the first GCN memset of Y. Total = 58,656,000 bytes (same as round-2 build).
constexpr size_t OFF_DEG = 0;                                  // 256,000 B
constexpr size_t OFF_A1  = 256000;
constexpr size_t OFF_B1  = OFF_A1 + 3840 * 4;
constexpr size_t OFF_A2  = OFF_B1 + 3840 * 4;
constexpr size_t OFF_B2  = OFF_A2 + 128 * 4;
constexpr size_t OFF_H   = 288000;                             // Nn*100*4 = 25,600,000
constexpr size_t OFF_T   = OFF_H + (size_t)Nn * 100 * 4;       // Nn*64*4
constexpr size_t OFF_Y   = OFF_T + (size_t)Nn * 64 * 4;        // Nn*64*4
constexpr size_t OFF_W1F = OFF_Y;                              // 983,040 shorts = 1,966,080 B
constexpr size_t OFF_W2F = OFF_Y + 2000000;                    // 860,160 shorts = 1,720,320 B
constexpr size_t WS_BYTES = OFF_Y + (size_t)Nn * 64 * 4;       // 58,656,000

// ---------------- bf16 helpers ----------------
__device__ inline unsigned short f2bf_rne(float v) {
    union { float f; unsigned u; } a; a.f = v;
    unsigned r = a.u + 0x7fffu + ((a.u >> 16) & 1u);
    return (unsigned short)(r >> 16);
}
__device__ inline float bf2f(unsigned short b) {
    union { unsigned u; float f; } a; a.u = ((unsigned)b) << 16; return a.f;
}

typedef __attribute__((ext_vector_type(8))) short bf16x8;
typedef __attribute__((ext_vector_type(4))) float f32x4;

// ---------------- small prep kernels ----------------
__global__ __launch_bounds__(TPB) void prep_bn(
    const float* __restrict__ b1, const float* __restrict__ g1,
    const float* __restrict__ be1, const float* __restrict__ m1,
    const float* __restrict__ v1,
    const float* __restrict__ b2, const float* __restrict__ g2,
    const float* __restrict__ be2, const float* __restrict__ m2,
    const float* __restrict__ v2,
    float* __restrict__ A1, float* __restrict__ B1,
    float* __restrict__ A2, float* __restrict__ B2)
{
    int i = blockIdx.x * TPB + threadIdx.x;
    if (i < HID) {
        float s = g1[i] * rsqrtf(v1[i] + EPS);
        A1[i] = s;
        B1[i] = fmaf(b1[i] - m1[i], s, be1[i]);
    }
    int k = i - HID;
    if (k >= 0 && k < 100) {
        float s = g2[k] * rsqrtf(v2[k] + EPS);
        A2[k] = s;
        B2[k] = fmaf(b2[k] - m2[k], s, be2[k]);
    }
}

__global__ __launch_bounds__(TPB) void deg_init(float* __restrict__ deg)
{
    int i = blockIdx.x * TPB + threadIdx.x;
    if (i < Nn) deg[i] = 1.f;
}

__global__ __launch_bounds__(TPB) void deg_count(const int* __restrict__ dst,
                                                 float* __restrict__ deg)
{
    int e = blockIdx.x * TPB + threadIdx.x;
    if (e < Ne) atomicAdd(&deg[dst[e]], 1.f);
}

__global__ __launch_bounds__(TPB) void deg_fin(float* __restrict__ deg)
{
    int i = blockIdx.x * TPB + threadIdx.x;
    if (i < Nn) deg[i] = rsqrtf(deg[i]);
}

// W1F[c][nt(4)][ks8(8)][lane(64)][8]: B-frags of W1' = W1*A1[col], rows 0-99 (pad 128),
// ks8 0-3 = hi split, 4-7 = lo split. 122,880 threads, each writes 8 bf16 (uint4).
__global__ __launch_bounds__(TPB) void prep_w1f(
    const float* __restrict__ W1, const float* __restrict__ A1,
    unsigned short* __restrict__ W1F)
{
    int t = blockIdx.x * TPB + threadIdx.x;           // < 122880
    int lane = t & 63, ks8 = (t >> 6) & 7, nt = (t >> 9) & 3, c = t >> 11;
    int col = c * 64 + nt * 16 + (lane & 15);
    int kbase = (ks8 & 3) * 32 + ((lane >> 4) << 3);
    bool lo = ks8 >= 4;
    float scale = A1[col];
    unsigned short outv[8];
#pragma unroll
    for (int e = 0; e < 8; ++e) {
        int k = kbase + e;
        float v = (k < 100) ? W1[(size_t)k * HID + col] * scale : 0.f;
        unsigned short h = f2bf_rne(v);
        outv[e] = lo ? f2bf_rne(v - bf2f(h)) : h;
    }
    *(uint4*)(W1F + (size_t)t * 8) = *(const uint4*)outv;
}

// W2F[c][nt2(7)][ksv(4)][lane][8]: B-frags of W2' = W2*A2[col], cols padded to 112.
// ksv 0-1 = hi (k 0-63 of chunk), 2-3 = lo. 107,520 threads.
__global__ __launch_bounds__(TPB) void prep_w2f(
    const float* __restrict__ W2, const float* __restrict__ A2,
    unsigned short* __restrict__ W2F)
{
    int t = blockIdx.x * TPB + threadIdx.x;           // < 107520
    int c = t / 1792, rem = t % 1792;
    int nt2 = rem >> 8, ksv = (rem >> 6) & 3, lane = rem & 63;
    int col = nt2 * 16 + (lane & 15);
    int kbase = c * 64 + (ksv & 1) * 32 + ((lane >> 4) << 3);
    bool lo = ksv >= 2;
    float scale = (col < 100) ? A2[col] : 0.f;
    unsigned short outv[8];
#pragma unroll
    for (int e = 0; e < 8; ++e) {
        float v = (col < 100) ? W2[(size_t)(kbase + e) * 100 + col] * scale : 0.f;
        unsigned short h = f2bf_rne(v);
        outv[e] = lo ? f2bf_rne(v - bf2f(h)) : h;
    }
    *(uint4*)(W2F + (size_t)t * 8) = *(const uint4*)outv;
}

// ---------------- MFMA FFN ----------------
// h0 = (relu(x@W1' + B1)) @ W2' + B2, fp32-accurate via hi/lo bf16 splits (3 passes each).
// 8 waves x 16 rows = 128 nodes/block; 60 chunks of 64 hidden; double-buffered weight LDS.
__global__ __launch_bounds__(512) void ffn_mfma(
    const float* __restrict__ x,
    const unsigned short* __restrict__ W1F,
    const unsigned short* __restrict__ W2F,
    const float* __restrict__ B1v,
    const float* __restrict__ B2v,
    float* __restrict__ h0)
{
    __shared__ unsigned short w1s[2][16384];   // [nt][ks8][lane][8]  (32 KB x2)
    __shared__ unsigned short w2s[2][14336];   // [nt2][ksv][lane][8] (28 KB x2)
    __shared__ unsigned short th_s[8][16][72]; // per-wave t hi  (stride 72: 16B-aligned rows)
    __shared__ unsigned short tl_s[8][16][72]; // per-wave t lo
    // total LDS = 65536 + 57344 + 36864 = 159,744 B (fits 160 KiB; 1 block/CU, 2 waves/SIMD)

    const int tid  = threadIdx.x;
    const int wave = tid >> 6, lane = tid & 63;
    const int lr = lane & 15, lhi = lane >> 4;
    const int node0 = blockIdx.x * 128 + wave * 16;

    // ---- x fragments (A-side, held in regs whole kernel): xh/xl, K1 padded to 128 ----
    bf16x8 xh[4], xl[4];
    {
        const float* xr = x + (size_t)(node0 + lr) * 100;
#pragma unroll
        for (int kq = 0; kq < 4; ++kq) {
            int k0 = kq * 32 + lhi * 8;
#pragma unroll
            for (int e = 0; e < 8; ++e) {
                float v = (k0 + e < 100) ? xr[k0 + e] : 0.f;
                unsigned short h = f2bf_rne(v);
                xh[kq][e] = (short)h;
                xl[kq][e] = (short)f2bf_rne(v - bf2f(h));
            }
        }
    }

    // ---- prologue: stage chunk 0 ----
    {
        const uint4* g1 = (const uint4*)W1F;
        for (int u = tid; u < 2048; u += 512) ((uint4*)w1s[0])[u] = g1[u];
        const uint4* g2 = (const uint4*)W2F;
        for (int u = tid; u < 1792; u += 512) ((uint4*)w2s[0])[u] = g2[u];
    }
    __syncthreads();

    f32x4 acc2[7];
#pragma unroll
    for (int i = 0; i < 7; ++i) acc2[i] = (f32x4){0.f, 0.f, 0.f, 0.f};

    for (int c = 0; c < 60; ++c) {
        const int buf = c & 1;

        // ---- GEMM1: t = x @ W1' (12 virtual K-steps: xh@Wh, xh@Wl, xl@Wh) ----
        f32x4 acc1[4];
#pragma unroll
        for (int i = 0; i < 4; ++i) acc1[i] = (f32x4){0.f, 0.f, 0.f, 0.f};
#pragma unroll
        for (int p = 0; p < 12; ++p) {
            const int bidx = (p < 8) ? p : (p - 8);
            const bf16x8 a = (p < 4) ? xh[p] : ((p < 8) ? xh[p - 4] : xl[p - 8]);
#pragma unroll
            for (int nt = 0; nt < 4; ++nt) {
                bf16x8 b = *(const bf16x8*)&w1s[buf][((nt * 8 + bidx) * 64 + lane) * 8];
                acc1[nt] = __builtin_amdgcn_mfma_f32_16x16x32_bf16(a, b, acc1[nt], 0, 0, 0);
            }
        }

        // ---- t phase: +bias, relu, hi/lo split into per-wave LDS ----
#pragma unroll
        for (int nt = 0; nt < 4; ++nt) {
            float bb = B1v[c * 64 + nt * 16 + lr];
#pragma unroll
            for (int r = 0; r < 4; ++r) {
                float v = fmaxf(acc1[nt][r] + bb, 0.f);
                unsigned short h = f2bf_rne(v);
                int row = lhi * 4 + r;
                th_s[wave][row][nt * 16 + lr] = h;
                tl_s[wave][row][nt * 16 + lr] = f2bf_rne(v - bf2f(h));
            }
        }
        __syncthreads();  // bar A: t ready; w1s[buf^1]/w2s[buf^1] free for restage

        // ---- issue next-chunk weight loads (hidden under GEMM2) ----
        uint4 st1[4], st2[4];
        if (c < 59) {
            const uint4* g1 = (const uint4*)(W1F + (size_t)(c + 1) * 16384);
#pragma unroll
            for (int i = 0; i < 4; ++i) st1[i] = g1[tid + 512 * i];
            const uint4* g2 = (const uint4*)(W2F + (size_t)(c + 1) * 14336);
#pragma unroll
            for (int i = 0; i < 3; ++i) st2[i] = g2[tid + 512 * i];
            if (tid < 256) st2[3] = g2[tid + 1536];
        }

        // ---- GEMM2: acc2 += t @ W2' (6 virtual K-steps: th@Wh, th@Wl, tl@Wh) ----
        bf16x8 ta[4];
        ta[0] = *(const bf16x8*)&th_s[wave][lr][lhi * 8];
        ta[1] = *(const bf16x8*)&th_s[wave][lr][32 + lhi * 8];
        ta[2] = *(const bf16x8*)&tl_s[wave][lr][lhi * 8];
        ta[3] = *(const bf16x8*)&tl_s[wave][lr][32 + lhi * 8];
#pragma unroll
        for (int p = 0; p < 6; ++p) {
            const int bidx = (p < 4) ? p : (p - 4);
            const bf16x8 a = (p < 4) ? ta[p & 1] : ta[2 + (p & 1)];
#pragma unroll
            for (int nt2 = 0; nt2 < 7; ++nt2) {
                bf16x8 b = *(const bf16x8*)&w2s[buf][((nt2 * 4 + bidx) * 64 + lane) * 8];
                acc2[nt2] = __builtin_amdgcn_mfma_f32_16x16x32_bf16(a, b, acc2[nt2], 0, 0, 0);
            }
        }

        // ---- write staged weights into the other buffer ----
        if (c < 59) {
#pragma unroll
            for (int i = 0; i < 4; ++i) ((uint4*)w1s[buf ^ 1])[tid + 512 * i] = st1[i];
#pragma unroll
            for (int i = 0; i < 3; ++i) ((uint4*)w2s[buf ^ 1])[tid + 512 * i] = st2[i];
            if (tid < 256) ((uint4*)w2s[buf ^ 1])[tid + 1536] = st2[3];
        }
        __syncthreads();  // bar B: GEMM2 done, next buffers staged
    }

    // ---- epilogue: + B2 (BN2 folded), store ----
#pragma unroll
    for (int nt2 = 0; nt2 < 7; ++nt2) {
        int col = nt2 * 16 + lr;
        if (col < 100) {
            float bb = B2v[col];
#pragma unroll
            for (int r = 0; r < 4; ++r) {
                int node = node0 + lhi * 4 + r;
                h0[(size_t)node * 100 + col] = acc2[nt2][r] + bb;
            }
        }
    }
}

// ---------------- GCN layer kernels ----------------
template <int FI2, int FO2>
__global__ __launch_bounds__(TPB) void gcn_transform(
    const float* __restrict__ h, const float* __restrict__ Wc,
    const float* __restrict__ dinv, float* __restrict__ t)
{
    __shared__ float wcs[FI2 * FO2];
    for (int idx = threadIdx.x; idx < FI2 * FO2; idx += TPB) wcs[idx] = Wc[idx];
    __syncthreads();
    int gid = blockIdx.x * TPB + threadIdx.x;
    int n = gid / FO2;
    int f = gid - n * FO2;
    const float* hr = h + (size_t)n * FI2;
    float a = 0.f;
#pragma unroll
    for (int i = 0; i < FI2; ++i) a = fmaf(hr[i], wcs[i * FO2 + f], a);
    t[gid] = a * dinv[n];
}

template <int FO2, int LOG2>
__global__ __launch_bounds__(TPB) void gcn_scatter(
    const int* __restrict__ src, const int* __restrict__ dst,
    const float* __restrict__ t, float* __restrict__ acc)
{
    int gid = blockIdx.x * TPB + threadIdx.x;
    int e = gid >> LOG2;
    int f = gid & (FO2 - 1);
    int s = src[e], d = dst[e];
    atomicAdd(&acc[(size_t)d * FO2 + f], t[(size_t)s * FO2 + f]);
}

template <int FO2, int LOG2>
__global__ __launch_bounds__(TPB) void gcn_finalize(
    const float* __restrict__ acc, const float* __restrict__ t,
    const float* __restrict__ dinv, const float* __restrict__ bc,
    float* __restrict__ hout)
{
    int gid = blockIdx.x * TPB + threadIdx.x;
    int n = gid >> LOG2;
    int f = gid & (FO2 - 1);
    hout[gid] = fmaxf(fmaf(dinv[n], acc[gid] + t[gid], bc[f]), 0.f);
}

__global__ __launch_bounds__(TPB) void final_fc(
    const float* __restrict__ h5, const float* __restrict__ Wf,
    const float* __restrict__ bfv, float* __restrict__ out)
{
    int g = blockIdx.x;
    float a0 = 0.f, a1 = 0.f;
    for (int i = threadIdx.x; i < NN * 4; i += TPB) {
        float hv = h5[(size_t)g * (NN * 4) + i];
        a0 = fmaf(hv, Wf[2 * i],     a0);
        a1 = fmaf(hv, Wf[2 * i + 1], a1);
    }
#pragma unroll
    for (int off = 32; off > 0; off >>= 1) {
        a0 += __shfl_down(a0, off);
        a1 += __shfl_down(a1, off);
    }
    __shared__ float r0[4], r1[4];
    int wid = threadIdx.x >> 6, lane = threadIdx.x & 63;
    if (lane == 0) { r0[wid] = a0; r1[wid] = a1; }
    __syncthreads();
    if (threadIdx.x == 0) {
        out[g * 2 + 0] = r0[0] + r0[1] + r0[2] + r0[3] + bfv[0];
        out[g * 2 + 1] = r1[0] + r1[1] + r1[2] + r1[3] + bfv[1];
    }
}

// ---------------- launch ----------------
extern "C" void kernel_launch(void* const* d_in, const int* in_sizes, int n_in,
                              void* d_out, int out_size, void* d_ws, size_t ws_size,
                              hipStream_t stream)
{
    const float* x   = (const float*)d_in[0];
    const int*   ei  = (const int*)d_in[1];
    const float* W1  = (const float*)d_in[2];
    const float* b1  = (const float*)d_in[3];
    const float* g1  = (const float*)d_in[4];
    const float* be1 = (const float*)d_in[5];
    const float* m1  = (const float*)d_in[6];
    const float* v1  = (const float*)d_in[7];
    const float* W2  = (const float*)d_in[8];
    const float* b2  = (const float*)d_in[9];
    const float* g2  = (const float*)d_in[10];
    const float* be2 = (const float*)d_in[11];
    const float* m2  = (const float*)d_in[12];
    const float* v2  = (const float*)d_in[13];
    const float* Wf  = (const float*)d_in[14];
    const float* bfv = (const float*)d_in[15];
    const float* Wc[5]  = {(const float*)d_in[16], (const float*)d_in[18],
                           (const float*)d_in[20], (const float*)d_in[22],
                           (const float*)d_in[24]};
    const float* bc[5]  = {(const float*)d_in[17], (const float*)d_in[19],
                           (const float*)d_in[21], (const float*)d_in[23],
                           (const float*)d_in[25]};

    const int* srcp = ei;
    const int* dstp = ei + Ne;

    char* wsb = (char*)d_ws;
    float* deg = (float*)(wsb + OFF_DEG);
    float* A1  = (float*)(wsb + OFF_A1);
    float* B1  = (float*)(wsb + OFF_B1);
    float* A2  = (float*)(wsb + OFF_A2);
    float* B2  = (float*)(wsb + OFF_B2);
    float* H   = (float*)(wsb + OFF_H);
    float* T   = (float*)(wsb + OFF_T);
    float* Y   = (float*)(wsb + OFF_Y);
    unsigned short* W1F = (unsigned short*)(wsb + OFF_W1F);  // aliases Y (dead then)
    unsigned short* W2F = (unsigned short*)(wsb + OFF_W2F);  // aliases Y (dead then)
    float* out = (float*)d_out;

    // degree / dinv
    deg_init<<<Nn / TPB, TPB, 0, stream>>>(deg);
    deg_count<<<Ne / TPB, TPB, 0, stream>>>(dstp, deg);
    deg_fin<<<Nn / TPB, TPB, 0, stream>>>(deg);

    // BN constants, then frag-major scaled/split weights
    prep_bn<<<(HID + 100 + TPB - 1) / TPB, TPB, 0, stream>>>(
        b1, g1, be1, m1, v1, b2, g2, be2, m2, v2, A1, B1, A2, B2);
    prep_w1f<<<480, TPB, 0, stream>>>(W1, A1, W1F);
    prep_w2f<<<420, TPB, 0, stream>>>(W2, A2, W2F);

    // fused MFMA FFN -> H = h0 [Nn,100]
    ffn_mfma<<<Nn / 128, 512, 0, stream>>>(x, W1F, W2F, B1, B2, H);

    // ---- GCN layer 1: H(100) -> H(64) ----
    gcn_transform<100, 64><<<(size_t)Nn * 64 / TPB, TPB, 0, stream>>>(H, Wc[0], deg, T);
    hipMemsetAsync(Y, 0, (size_t)Nn * 64 * sizeof(float), stream);
    gcn_scatter<64, 6><<<(size_t)Ne * 64 / TPB, TPB, 0, stream>>>(srcp, dstp, T, Y);
    gcn_finalize<64, 6><<<(size_t)Nn * 64 / TPB, TPB, 0, stream>>>(Y, T, deg, bc[0], H);

    // ---- layer 2: H(64) -> H(32) ----
    gcn_transform<64, 32><<<(size_t)Nn * 32 / TPB, TPB, 0, stream>>>(H, Wc[1], deg, T);
    hipMemsetAsync(Y, 0, (size_t)Nn * 32 * sizeof(float), stream);
    gcn_scatter<32, 5><<<(size_t)Ne * 32 / TPB, TPB, 0, stream>>>(srcp, dstp, T, Y);
    gcn_finalize<32, 5><<<(size_t)Nn * 32 / TPB, TPB, 0, stream>>>(Y, T, deg, bc[1], H);

    // ---- layer 3: H(32) -> H(16) ----
    gcn_transform<32, 16><<<(size_t)Nn * 16 / TPB, TPB, 0, stream>>>(H, Wc[2], deg, T);
    hipMemsetAsync(Y, 0, (size_t)Nn * 16 * sizeof(float), stream);
    gcn_scatter<16, 4><<<(size_t)Ne * 16 / TPB, TPB, 0, stream>>>(srcp, dstp, T, Y);
    gcn_finalize<16, 4><<<(size_t)Nn * 16 / TPB, TPB, 0, stream>>>(Y, T, deg, bc[2], H);

    // ---- layer 4: H(16) -> H(8) ----
    gcn_transform<16, 8><<<(size_t)Nn * 8 / TPB, TPB, 0, stream>>>(H, Wc[3], deg, T);
    hipMemsetAsync(Y, 0, (size_t)Nn * 8 * sizeof(float), stream);
    gcn_scatter<8, 3><<<(size_t)Ne * 8 / TPB, TPB, 0, stream>>>(srcp, dstp, T, Y);
    gcn_finalize<8, 3><<<(size_t)Nn * 8 / TPB, TPB, 0, stream>>>(Y, T, deg, bc[3], H);

    // ---- layer 5: H(8) -> H(4) ----
    gcn_transform<8, 4><<<(size_t)Nn * 4 / TPB, TPB, 0, stream>>>(H, Wc[4], deg, T);
    hipMemsetAsync(Y, 0, (size_t)Nn * 4 * sizeof(float), stream);
    gcn_scatter<4, 2><<<(size_t)Ne * 4 / TPB, TPB, 0, stream>>>(srcp, dstp, T, Y);
    gcn_finalize<4, 2><<<(size_t)Nn * 4 / TPB, TPB, 0, stream>>>(Y, T, deg, bc[4], H);

    // final FC (H holds [Nn,4] == [64, 4000] flat)
    final_fc<<<NG, TPB, 0, stream>>>(H, Wf, bfv, out);
}

// Round 6
// 1345.356 us; speedup vs baseline: 3.9199x; 1.3400x over previous
//
#include <hip/hip_runtime.h>

#define TPB 256

constexpr int NG = 64, NN = 1000;
constexpr int Nn = NG * NN;          // 64000 nodes
constexpr int Ne = Nn * 32;          // 2048000 edges
constexpr int HID = 3840;
constexpr float EPS = 1e-5f;

// ---------------- workspace layout (BYTE offsets, all disjoint, 16B-aligned) ----------------
constexpr size_t OFF_DEG  = 0;                         // Nn*4 = 256,000
constexpr size_t OFF_A1   = 256000;                    // 3840*4
constexpr size_t OFF_B1   = OFF_A1 + 15360;
constexpr size_t OFF_A2   = OFF_B1 + 15360;            // 128*4
constexpr size_t OFF_B2   = OFF_A2 + 512;              // ends 287,744
constexpr size_t OFF_OFFA = 287744;                    // (Nn+1)*4 -> pad 256,016
constexpr size_t OFF_CUR  = 543760;                    // Nn*4
constexpr size_t OFF_ADJ  = 799760;                    // Ne*4 = 8,192,000
constexpr size_t OFF_W1F  = 8991760;                   // 983,040 shorts = 1,966,080
constexpr size_t OFF_W2F  = 10957840;                  // 860,160 shorts = 1,720,320
constexpr size_t OFF_H    = 12678160;                  // Nn*100*4 = 25,600,000
constexpr size_t OFF_T    = 38278160;                  // Nn*64*4 = 16,384,000
constexpr size_t WS_BYTES = 54662160;                  // 54.7 MB total

// ---------------- bf16 helpers ----------------
__device__ inline unsigned short f2bf_rne(float v) {
    union { float f; unsigned u; } a; a.f = v;
    unsigned r = a.u + 0x7fffu + ((a.u >> 16) & 1u);
    return (unsigned short)(r >> 16);
}
__device__ inline float bf2f(unsigned short b) {
    union { unsigned u; float f; } a; a.u = ((unsigned)b) << 16; return a.f;
}

typedef __attribute__((ext_vector_type(8))) short bf16x8;
typedef __attribute__((ext_vector_type(4))) float f32x4;

// ---------------- small prep kernels ----------------
__global__ __launch_bounds__(TPB) void prep_bn(
    const float* __restrict__ b1, const float* __restrict__ g1,
    const float* __restrict__ be1, const float* __restrict__ m1,
    const float* __restrict__ v1,
    const float* __restrict__ b2, const float* __restrict__ g2,
    const float* __restrict__ be2, const float* __restrict__ m2,
    const float* __restrict__ v2,
    float* __restrict__ A1, float* __restrict__ B1,
    float* __restrict__ A2, float* __restrict__ B2)
{
    int i = blockIdx.x * TPB + threadIdx.x;
    if (i < HID) {
        float s = g1[i] * rsqrtf(v1[i] + EPS);
        A1[i] = s;
        B1[i] = fmaf(b1[i] - m1[i], s, be1[i]);
    }
    int k = i - HID;
    if (k >= 0 && k < 100) {
        float s = g2[k] * rsqrtf(v2[k] + EPS);
        A2[k] = s;
        B2[k] = fmaf(b2[k] - m2[k], s, be2[k]);
    }
}

__global__ __launch_bounds__(TPB) void deg_init(float* __restrict__ deg)
{
    int i = blockIdx.x * TPB + threadIdx.x;
    if (i < Nn) deg[i] = 1.f;
}

__global__ __launch_bounds__(TPB) void deg_count(const int* __restrict__ dst,
                                                 float* __restrict__ deg)
{
    int e = blockIdx.x * TPB + threadIdx.x;
    if (e < Ne) atomicAdd(&deg[dst[e]], 1.f);
}

__global__ __launch_bounds__(TPB) void deg_fin(float* __restrict__ deg)
{
    int i = blockIdx.x * TPB + threadIdx.x;
    if (i < Nn) deg[i] = rsqrtf(deg[i]);
}

// exclusive scan of edge-counts (deg-1) -> off[0..Nn]; single block, shfl-based
__global__ __launch_bounds__(1024) void scan_off(const float* __restrict__ deg,
                                                 int* __restrict__ off)
{
    __shared__ int wsum[16];
    __shared__ int wpre[16];
    __shared__ int tot_s;
    __shared__ int carry_s;
    const int tid = threadIdx.x, lane = tid & 63, wid = tid >> 6;
    if (tid == 0) carry_s = 0;
    __syncthreads();
    for (int base = 0; base < Nn; base += 1024) {
        int i = base + tid;
        int v = (i < Nn) ? (int)(deg[i] + 0.5f) - 1 : 0;
        int acc = v;
#pragma unroll
        for (int s = 1; s < 64; s <<= 1) {
            int t = __shfl_up(acc, s);
            if (lane >= s) acc += t;
        }
        if (lane == 63) wsum[wid] = acc;
        __syncthreads();
        if (wid == 0) {
            int wv = (lane < 16) ? wsum[lane] : 0;
            int wacc = wv;
#pragma unroll
            for (int s = 1; s < 16; s <<= 1) {
                int t = __shfl_up(wacc, s);
                if (lane >= s) wacc += t;
            }
            if (lane < 16) wpre[lane] = wacc - wv;   // exclusive wave prefix
            if (lane == 15) tot_s = wacc;            // chunk total
        }
        __syncthreads();
        if (i < Nn) off[i] = carry_s + wpre[wid] + (acc - v);
        __syncthreads();
        if (tid == 0) carry_s += tot_s;
    }
    if (tid == 0) off[Nn] = carry_s;   // == Ne
}

// ticket-fill adjacency: adj[off[d] + ticket] = src
__global__ __launch_bounds__(TPB) void csr_fill(
    const int* __restrict__ src, const int* __restrict__ dst,
    const int* __restrict__ off, int* __restrict__ cur, int* __restrict__ adj)
{
    int e = blockIdx.x * TPB + threadIdx.x;
    if (e < Ne) {
        int d = dst[e];
        int p = atomicAdd(&cur[d], 1);
        adj[off[d] + p] = src[e];
    }
}

// W1F[c][nt(4)][ks8(8)][lane(64)][8]: B-frags of W1' = W1*A1[col]; ks8 0-3 hi, 4-7 lo.
__global__ __launch_bounds__(TPB) void prep_w1f(
    const float* __restrict__ W1, const float* __restrict__ A1,
    unsigned short* __restrict__ W1F)
{
    int t = blockIdx.x * TPB + threadIdx.x;           // < 122880
    int lane = t & 63, ks8 = (t >> 6) & 7, nt = (t >> 9) & 3, c = t >> 11;
    int col = c * 64 + nt * 16 + (lane & 15);
    int kbase = (ks8 & 3) * 32 + ((lane >> 4) << 3);
    bool lo = ks8 >= 4;
    float scale = A1[col];
    unsigned short outv[8];
#pragma unroll
    for (int e = 0; e < 8; ++e) {
        int k = kbase + e;
        float v = (k < 100) ? W1[(size_t)k * HID + col] * scale : 0.f;
        unsigned short h = f2bf_rne(v);
        outv[e] = lo ? f2bf_rne(v - bf2f(h)) : h;
    }
    *(uint4*)(W1F + (size_t)t * 8) = *(const uint4*)outv;
}

// W2F[c][nt2(7)][ksv(4)][lane][8]: B-frags of W2' = W2*A2[col], cols padded to 112.
__global__ __launch_bounds__(TPB) void prep_w2f(
    const float* __restrict__ W2, const float* __restrict__ A2,
    unsigned short* __restrict__ W2F)
{
    int t = blockIdx.x * TPB + threadIdx.x;           // < 107520
    int c = t / 1792, rem = t % 1792;
    int nt2 = rem >> 8, ksv = (rem >> 6) & 3, lane = rem & 63;
    int col = nt2 * 16 + (lane & 15);
    int kbase = c * 64 + (ksv & 1) * 32 + ((lane >> 4) << 3);
    bool lo = ksv >= 2;
    float scale = (col < 100) ? A2[col] : 0.f;
    unsigned short outv[8];
#pragma unroll
    for (int e = 0; e < 8; ++e) {
        float v = (col < 100) ? W2[(size_t)(kbase + e) * 100 + col] * scale : 0.f;
        unsigned short h = f2bf_rne(v);
        outv[e] = lo ? f2bf_rne(v - bf2f(h)) : h;
    }
    *(uint4*)(W2F + (size_t)t * 8) = *(const uint4*)outv;
}

// ---------------- MFMA FFN ----------------
__global__ __launch_bounds__(512) void ffn_mfma(
    const float* __restrict__ x,
    const unsigned short* __restrict__ W1F,
    const unsigned short* __restrict__ W2F,
    const float* __restrict__ B1v,
    const float* __restrict__ B2v,
    float* __restrict__ h0)
{
    __shared__ unsigned short w1s[2][16384];
    __shared__ unsigned short w2s[2][14336];
    __shared__ unsigned short th_s[8][16][72];
    __shared__ unsigned short tl_s[8][16][72];

    const int tid  = threadIdx.x;
    const int wave = tid >> 6, lane = tid & 63;
    const int lr = lane & 15, lhi = lane >> 4;
    const int node0 = blockIdx.x * 128 + wave * 16;

    bf16x8 xh[4], xl[4];
    {
        const float* xr = x + (size_t)(node0 + lr) * 100;
#pragma unroll
        for (int kq = 0; kq < 4; ++kq) {
            int k0 = kq * 32 + lhi * 8;
#pragma unroll
            for (int e = 0; e < 8; ++e) {
                float v = (k0 + e < 100) ? xr[k0 + e] : 0.f;
                unsigned short h = f2bf_rne(v);
                xh[kq][e] = (short)h;
                xl[kq][e] = (short)f2bf_rne(v - bf2f(h));
            }
        }
    }

    {
        const uint4* g1 = (const uint4*)W1F;
        for (int u = tid; u < 2048; u += 512) ((uint4*)w1s[0])[u] = g1[u];
        const uint4* g2 = (const uint4*)W2F;
        for (int u = tid; u < 1792; u += 512) ((uint4*)w2s[0])[u] = g2[u];
    }
    __syncthreads();

    f32x4 acc2[7];
#pragma unroll
    for (int i = 0; i < 7; ++i) acc2[i] = (f32x4){0.f, 0.f, 0.f, 0.f};

    for (int c = 0; c < 60; ++c) {
        const int buf = c & 1;

        f32x4 acc1[4];
#pragma unroll
        for (int i = 0; i < 4; ++i) acc1[i] = (f32x4){0.f, 0.f, 0.f, 0.f};
#pragma unroll
        for (int p = 0; p < 12; ++p) {
            const int bidx = (p < 8) ? p : (p - 8);
            const bf16x8 a = (p < 4) ? xh[p] : ((p < 8) ? xh[p - 4] : xl[p - 8]);
#pragma unroll
            for (int nt = 0; nt < 4; ++nt) {
                bf16x8 b = *(const bf16x8*)&w1s[buf][((nt * 8 + bidx) * 64 + lane) * 8];
                acc1[nt] = __builtin_amdgcn_mfma_f32_16x16x32_bf16(a, b, acc1[nt], 0, 0, 0);
            }
        }

#pragma unroll
        for (int nt = 0; nt < 4; ++nt) {
            float bb = B1v[c * 64 + nt * 16 + lr];
#pragma unroll
            for (int r = 0; r < 4; ++r) {
                float v = fmaxf(acc1[nt][r] + bb, 0.f);
                unsigned short h = f2bf_rne(v);
                int row = lhi * 4 + r;
                th_s[wave][row][nt * 16 + lr] = h;
                tl_s[wave][row][nt * 16 + lr] = f2bf_rne(v - bf2f(h));
            }
        }
        __syncthreads();

        uint4 st1[4], st2[4];
        if (c < 59) {
            const uint4* g1 = (const uint4*)(W1F + (size_t)(c + 1) * 16384);
#pragma unroll
            for (int i = 0; i < 4; ++i) st1[i] = g1[tid + 512 * i];
            const uint4* g2 = (const uint4*)(W2F + (size_t)(c + 1) * 14336);
#pragma unroll
            for (int i = 0; i < 3; ++i) st2[i] = g2[tid + 512 * i];
            if (tid < 256) st2[3] = g2[tid + 1536];
        }

        bf16x8 ta[4];
        ta[0] = *(const bf16x8*)&th_s[wave][lr][lhi * 8];
        ta[1] = *(const bf16x8*)&th_s[wave][lr][32 + lhi * 8];
        ta[2] = *(const bf16x8*)&tl_s[wave][lr][lhi * 8];
        ta[3] = *(const bf16x8*)&tl_s[wave][lr][32 + lhi * 8];
#pragma unroll
        for (int p = 0; p < 6; ++p) {
            const int bidx = (p < 4) ? p : (p - 4);
            const bf16x8 a = (p < 4) ? ta[p & 1] : ta[2 + (p & 1)];
#pragma unroll
            for (int nt2 = 0; nt2 < 7; ++nt2) {
                bf16x8 b = *(const bf16x8*)&w2s[buf][((nt2 * 4 + bidx) * 64 + lane) * 8];
                acc2[nt2] = __builtin_amdgcn_mfma_f32_16x16x32_bf16(a, b, acc2[nt2], 0, 0, 0);
            }
        }

        if (c < 59) {
#pragma unroll
            for (int i = 0; i < 4; ++i) ((uint4*)w1s[buf ^ 1])[tid + 512 * i] = st1[i];
#pragma unroll
            for (int i = 0; i < 3; ++i) ((uint4*)w2s[buf ^ 1])[tid + 512 * i] = st2[i];
            if (tid < 256) ((uint4*)w2s[buf ^ 1])[tid + 1536] = st2[3];
        }
        __syncthreads();
    }

#pragma unroll
    for (int nt2 = 0; nt2 < 7; ++nt2) {
        int col = nt2 * 16 + lr;
        if (col < 100) {
            float bb = B2v[col];
#pragma unroll
            for (int r = 0; r < 4; ++r) {
                int node = node0 + lhi * 4 + r;
                h0[(size_t)node * 100 + col] = acc2[nt2][r] + bb;
            }
        }
    }
}

// ---------------- GCN layer kernels ----------------
// t[n,f] = dinv[n] * dot(h[n,:], Wc[:,f])
template <int FI2, int FO2>
__global__ __launch_bounds__(TPB) void gcn_transform(
    const float* __restrict__ h, const float* __restrict__ Wc,
    const float* __restrict__ dinv, float* __restrict__ t)
{
    __shared__ float wcs[FI2 * FO2];
    for (int idx = threadIdx.x; idx < FI2 * FO2; idx += TPB) wcs[idx] = Wc[idx];
    __syncthreads();
    int gid = blockIdx.x * TPB + threadIdx.x;
    int n = gid / FO2;
    int f = gid - n * FO2;
    const float* hr = h + (size_t)n * FI2;
    float a = 0.f;
#pragma unroll
    for (int i = 0; i < FI2; ++i) a = fmaf(hr[i], wcs[i * FO2 + f], a);
    t[gid] = a * dinv[n];
}

// fused aggregate(+self)+BN-bias+relu via CSR gather: one wave per dst node.
// out[d,f] = relu(dinv[d]*(sum_{s in adj[d]} t[s,f] + t[d,f]) + bc[f])
template <int FO, int LOG2FO>
__global__ __launch_bounds__(TPB) void gcn_gather(
    const int* __restrict__ off, const int* __restrict__ adj,
    const float* __restrict__ t, const float* __restrict__ dinv,
    const float* __restrict__ bc, float* __restrict__ hout)
{
    constexpr int SUB = 64 >> LOG2FO;          // neighbor slices per wave
    const int wave = threadIdx.x >> 6;
    const int lane = threadIdx.x & 63;
    const int d = blockIdx.x * 4 + wave;
    const int f = lane & (FO - 1);
    const int sub = lane >> LOG2FO;

    const int b = off[d], e = off[d + 1];
    float acc = 0.f;
    for (int j = b + sub; j < e; j += SUB) {
        int s = adj[j];
        acc += t[(size_t)s * FO + f];
    }
#pragma unroll
    for (int m = FO; m < 64; m <<= 1) acc += __shfl_xor(acc, m);
    float total = acc + t[(size_t)d * FO + f];
    float o = fmaxf(fmaf(dinv[d], total, bc[f]), 0.f);
    if (sub == 0) hout[(size_t)d * FO + f] = o;
}

__global__ __launch_bounds__(TPB) void final_fc(
    const float* __restrict__ h5, const float* __restrict__ Wf,
    const float* __restrict__ bfv, float* __restrict__ out)
{
    int g = blockIdx.x;
    float a0 = 0.f, a1 = 0.f;
    for (int i = threadIdx.x; i < NN * 4; i += TPB) {
        float hv = h5[(size_t)g * (NN * 4) + i];
        a0 = fmaf(hv, Wf[2 * i],     a0);
        a1 = fmaf(hv, Wf[2 * i + 1], a1);
    }
#pragma unroll
    for (int off = 32; off > 0; off >>= 1) {
        a0 += __shfl_down(a0, off);
        a1 += __shfl_down(a1, off);
    }
    __shared__ float r0[4], r1[4];
    int wid = threadIdx.x >> 6, lane = threadIdx.x & 63;
    if (lane == 0) { r0[wid] = a0; r1[wid] = a1; }
    __syncthreads();
    if (threadIdx.x == 0) {
        out[g * 2 + 0] = r0[0] + r0[1] + r0[2] + r0[3] + bfv[0];
        out[g * 2 + 1] = r1[0] + r1[1] + r1[2] + r1[3] + bfv[1];
    }
}

// ---------------- launch ----------------
extern "C" void kernel_launch(void* const* d_in, const int* in_sizes, int n_in,
                              void* d_out, int out_size, void* d_ws, size_t ws_size,
                              hipStream_t stream)
{
    const float* x   = (const float*)d_in[0];
    const int*   ei  = (const int*)d_in[1];
    const float* W1  = (const float*)d_in[2];
    const float* b1  = (const float*)d_in[3];
    const float* g1  = (const float*)d_in[4];
    const float* be1 = (const float*)d_in[5];
    const float* m1  = (const float*)d_in[6];
    const float* v1  = (const float*)d_in[7];
    const float* W2  = (const float*)d_in[8];
    const float* b2  = (const float*)d_in[9];
    const float* g2  = (const float*)d_in[10];
    const float* be2 = (const float*)d_in[11];
    const float* m2  = (const float*)d_in[12];
    const float* v2  = (const float*)d_in[13];
    const float* Wf  = (const float*)d_in[14];
    const float* bfv = (const float*)d_in[15];
    const float* Wc[5]  = {(const float*)d_in[16], (const float*)d_in[18],
                           (const float*)d_in[20], (const float*)d_in[22],
                           (const float*)d_in[24]};
    const float* bc[5]  = {(const float*)d_in[17], (const float*)d_in[19],
                           (const float*)d_in[21], (const float*)d_in[23],
                           (const float*)d_in[25]};

    const int* srcp = ei;
    const int* dstp = ei + Ne;

    char* wsb = (char*)d_ws;
    float* deg = (float*)(wsb + OFF_DEG);
    float* A1  = (float*)(wsb + OFF_A1);
    float* B1  = (float*)(wsb + OFF_B1);
    float* A2  = (float*)(wsb + OFF_A2);
    float* B2  = (float*)(wsb + OFF_B2);
    int*   off = (int*)(wsb + OFF_OFFA);
    int*   cur = (int*)(wsb + OFF_CUR);
    int*   adj = (int*)(wsb + OFF_ADJ);
    unsigned short* W1F = (unsigned short*)(wsb + OFF_W1F);
    unsigned short* W2F = (unsigned short*)(wsb + OFF_W2F);
    float* H   = (float*)(wsb + OFF_H);
    float* T   = (float*)(wsb + OFF_T);
    float* out = (float*)d_out;

    // degree counts -> CSR offsets -> dinv
    deg_init<<<Nn / TPB, TPB, 0, stream>>>(deg);
    deg_count<<<Ne / TPB, TPB, 0, stream>>>(dstp, deg);
    scan_off<<<1, 1024, 0, stream>>>(deg, off);
    deg_fin<<<Nn / TPB, TPB, 0, stream>>>(deg);

    // adjacency fill
    hipMemsetAsync(cur, 0, (size_t)Nn * 4, stream);
    csr_fill<<<Ne / TPB, TPB, 0, stream>>>(srcp, dstp, off, cur, adj);

    // BN constants + frag-major scaled/split weights
    prep_bn<<<(HID + 100 + TPB - 1) / TPB, TPB, 0, stream>>>(
        b1, g1, be1, m1, v1, b2, g2, be2, m2, v2, A1, B1, A2, B2);
    prep_w1f<<<480, TPB, 0, stream>>>(W1, A1, W1F);
    prep_w2f<<<420, TPB, 0, stream>>>(W2, A2, W2F);

    // fused MFMA FFN -> H = h0 [Nn,100]
    ffn_mfma<<<Nn / 128, 512, 0, stream>>>(x, W1F, W2F, B1, B2, H);

    // ---- GCN layers: transform -> fused gather/finalize (in-place H) ----
    gcn_transform<100, 64><<<(size_t)Nn * 64 / TPB, TPB, 0, stream>>>(H, Wc[0], deg, T);
    gcn_gather<64, 6><<<Nn / 4, TPB, 0, stream>>>(off, adj, T, deg, bc[0], H);

    gcn_transform<64, 32><<<(size_t)Nn * 32 / TPB, TPB, 0, stream>>>(H, Wc[1], deg, T);
    gcn_gather<32, 5><<<Nn / 4, TPB, 0, stream>>>(off, adj, T, deg, bc[1], H);

    gcn_transform<32, 16><<<(size_t)Nn * 16 / TPB, TPB, 0, stream>>>(H, Wc[2], deg, T);
    gcn_gather<16, 4><<<Nn / 4, TPB, 0, stream>>>(off, adj, T, deg, bc[2], H);

    gcn_transform<16, 8><<<(size_t)Nn * 8 / TPB, TPB, 0, stream>>>(H, Wc[3], deg, T);
    gcn_gather<8, 3><<<Nn / 4, TPB, 0, stream>>>(off, adj, T, deg, bc[3], H);

    gcn_transform<8, 4><<<(size_t)Nn * 4 / TPB, TPB, 0, stream>>>(H, Wc[4], deg, T);
    gcn_gather<4, 2><<<Nn / 4, TPB, 0, stream>>>(off, adj, T, deg, bc[4], H);

    // final FC (H holds [Nn,4] == [64, 4000] flat)
    final_fc<<<NG, TPB, 0, stream>>>(H, Wf, bfv, out);
}